// Round 2
// baseline (115.143 us; speedup 1.0000x reference)
//
#include <hip/hip_runtime.h>
#include <hip/hip_bf16.h>

// Interpolate1D: z = interp(cumsum(softmax(x@W + b)), y); outputs (z[B], x[B,64], logdet[B]+log|slope|)
// B=524288, D=64, R=256.
//
// Strategy: bf16 MFMA for the GEMM (f32 vector ALU would be compute-bound at ~109us;
// bf16 MFMA ~7us -> memory-bound at ~44us floor). Never materialize cumsum: per row only
// denom / prefix-sum(<=start) / exp(l[start+1]) are needed (reductions, not scans).

#define NB 524288
#define ND 64
#define NR 256
#define NTILES (NB / 64)

typedef __attribute__((ext_vector_type(4))) float f32x4;
typedef __attribute__((ext_vector_type(8))) __bf16 bf16x8;

static __device__ __forceinline__ unsigned short f2b(float f) {
    __hip_bfloat16 h = __float2bfloat16(f);
    return __builtin_bit_cast(unsigned short, h);
}

__global__ __launch_bounds__(256) void interp1d_kernel(
    const float* __restrict__ y, const float* __restrict__ x,
    const float* __restrict__ W, const float* __restrict__ bias,
    const float* __restrict__ logdet, const float* __restrict__ bp,
    float* __restrict__ out)
{
    // LDS: packed W (B-fragment layout) 32KB + x tile (row-padded) 9KB + tables
    __shared__ unsigned short sW[2 * 16 * 64 * 8];   // [kb][n][lane][i] bf16
    __shared__ unsigned short sX[64 * 72];           // 64 rows x 64 k, stride 72 (pad kills b128 bank conflict)
    __shared__ float sBP[256];
    __shared__ float sBias[256];
    __shared__ float sY[64];
    __shared__ int   sS[64];

    const int t = threadIdx.x;

    // --- one-time per block: stage base_points, bias, and W packed into MFMA B-frag layout ---
    sBP[t]   = bp[t];
    sBias[t] = bias[t];
    // B-frag for mfma_f32_16x16x32_bf16: lane provides col=lane%16, k=(lane/16)*8+i.
    // Element (kb,n,lane,i) = W[k=kb*32+(lane>>4)*8+i][col=n*16+(lane&15)].
    for (int k = 0; k < 64; ++k) {
        float wv = W[k * 256 + t];                       // coalesced: t is the column
        int lane16 = ((k >> 3) & 3) * 16 + (t & 15);
        int n  = t >> 4;
        int kb = k >> 5;
        int i  = k & 7;
        sW[((kb * 16 + n) * 64 + lane16) * 8 + i] = f2b(wv);
    }
    __syncthreads();

    const int lane    = t & 63;
    const int rowBase = (t >> 6) * 16;     // wave's 16-row slice of the 64-row tile
    const int colb    = lane & 15;
    const int kHalf   = lane >> 4;

    for (int tile = blockIdx.x; tile < NTILES; tile += gridDim.x) {
        const int m0 = tile * 64;

        // --- stage x tile: f32 passthrough to out, bf16 copy to LDS ---
        {
            const f32x4* xg = reinterpret_cast<const f32x4*>(x) + (size_t)m0 * 16;
            f32x4* xo = reinterpret_cast<f32x4*>(out + NB) + (size_t)m0 * 16;
            #pragma unroll
            for (int it = 0; it < 4; ++it) {
                int f = it * 256 + t;          // 1024 float4 = 64 rows x 64 cols
                f32x4 v = xg[f];
                xo[f] = v;
                int r = f >> 4, c4 = (f & 15) << 2;
                ushort4 h;
                h.x = f2b(v[0]); h.y = f2b(v[1]); h.z = f2b(v[2]); h.w = f2b(v[3]);
                *reinterpret_cast<ushort4*>(&sX[r * 72 + c4]) = h;
            }
            if (t < 64) {
                float yv = y[m0 + t];
                // searchsorted(bp, y, 'right')-1: guess then fix up against actual bp values
                int s = (int)floorf(yv * 255.0f);
                s = min(254, max(0, s));
                while (s < 254 && sBP[s + 1] <= yv) ++s;
                while (s > 0 && sBP[s] > yv) --s;
                sY[t] = yv;
                sS[t] = s;
            }
        }
        __syncthreads();

        // --- MFMA: 16 rows x 256 cols per wave, K=64 in two k-halves ---
        // A-frag: row=lane%16, k=(lane/16)*8+i (contiguous 16B per lane, pad -> <=2-way bank alias)
        bf16x8 a0 = *reinterpret_cast<const bf16x8*>(&sX[(rowBase + colb) * 72 + kHalf * 8]);
        bf16x8 a1 = *reinterpret_cast<const bf16x8*>(&sX[(rowBase + colb) * 72 + 32 + kHalf * 8]);

        f32x4 acc[16];
        #pragma unroll
        for (int n = 0; n < 16; ++n) {
            bf16x8 b0 = *reinterpret_cast<const bf16x8*>(&sW[(n * 64 + lane) * 8]);
            bf16x8 b1 = *reinterpret_cast<const bf16x8*>(&sW[((16 + n) * 64 + lane) * 8]);
            f32x4 c = {0.f, 0.f, 0.f, 0.f};
            c = __builtin_amdgcn_mfma_f32_16x16x32_bf16(a0, b0, c, 0, 0, 0);
            c = __builtin_amdgcn_mfma_f32_16x16x32_bf16(a1, b1, c, 0, 0, 0);
            acc[n] = c;
        }

        // --- epilogue: per-row denom / prefix(<=s) / exp at s+1, reduced over the 16-lane group ---
        // C layout: col = n*16 + (lane&15), row = rowBase + (lane>>4)*4 + j
        int sArr[4];
        #pragma unroll
        for (int j = 0; j < 4; ++j) sArr[j] = sS[rowBase + kHalf * 4 + j];

        float denom[4] = {0, 0, 0, 0}, f0s[4] = {0, 0, 0, 0}, p1[4] = {0, 0, 0, 0};
        #pragma unroll
        for (int n = 0; n < 16; ++n) {
            const int col = n * 16 + colb;
            const float bn = sBias[col];
            #pragma unroll
            for (int j = 0; j < 4; ++j) {
                float e = __expf(acc[n][j] + bn);   // logits ~N(0,0.4): no max-subtract needed
                denom[j] += e;
                if (col <= sArr[j])    f0s[j] += e;
                if (col == sArr[j] + 1) p1[j] += e;
            }
        }
        #pragma unroll
        for (int off = 8; off; off >>= 1) {
            #pragma unroll
            for (int j = 0; j < 4; ++j) {
                denom[j] += __shfl_xor(denom[j], off, 64);
                f0s[j]   += __shfl_xor(f0s[j], off, 64);
                p1[j]    += __shfl_xor(p1[j], off, 64);
            }
        }

        if (colb == 0) {  // lanes 0,16,32,48: each owns 4 consecutive rows -> float4 stores
            const int rloc = rowBase + kHalf * 4;
            const int row = m0 + rloc;
            f32x4 ld = *reinterpret_cast<const f32x4*>(logdet + row);
            f32x4 zv, dv;
            #pragma unroll
            for (int j = 0; j < 4; ++j) {
                int s = sS[rloc + j];
                float x0 = sBP[s], x1 = sBP[s + 1];
                float inv = 1.0f / denom[j];
                float f0 = f0s[j] * inv;
                float slope = (p1[j] * inv) / (x1 - x0);
                float yv = sY[rloc + j];
                zv[j] = fmaf(slope, yv - x0, f0);
                dv[j] = ld[j] + __logf(fabsf(slope));
            }
            *reinterpret_cast<f32x4*>(out + row) = zv;
            *reinterpret_cast<f32x4*>(out + (size_t)NB * 65 + row) = dv;
        }
        __syncthreads();   // protect sX/sY/sS before next tile's staging
    }
}

extern "C" void kernel_launch(void* const* d_in, const int* in_sizes, int n_in,
                              void* d_out, int out_size, void* d_ws, size_t ws_size,
                              hipStream_t stream) {
    (void)in_sizes; (void)n_in; (void)out_size; (void)d_ws; (void)ws_size;
    const float* y      = (const float*)d_in[0];
    const float* x      = (const float*)d_in[1];
    const float* W      = (const float*)d_in[2];
    const float* b      = (const float*)d_in[3];
    const float* logdet = (const float*)d_in[4];
    const float* bp     = (const float*)d_in[5];
    float* out = (float*)d_out;
    interp1d_kernel<<<dim3(2048), dim3(256), 0, stream>>>(y, x, W, b, logdet, bp, out);
}